// Round 9
// baseline (12739.207 us; speedup 1.0000x reference)
//
#include <hip/hip_runtime.h>
#include <math.h>

#define B_   256
#define N_   1536
#define OBS_ 20
#define HOR_ 30

typedef __bf16 bf16;
typedef bf16  bf16x8 __attribute__((ext_vector_type(8)));
typedef float f32x4  __attribute__((ext_vector_type(4)));

__device__ __forceinline__ f32x4 MF(bf16x8 a, bf16x8 b, f32x4 c) {
    return __builtin_amdgcn_mfma_f32_16x16x32_bf16(a, b, c, 0, 0, 0);
}

// ---------------------------------------------------------------------------
// Advisory phase-alignment barrier: RELAXED device atomics, NO fences.
// Correctness never depends on it (no cross-block data) — it only keeps the
// per-XCD blocks streaming the same weight phase for L2 residency.
// ---------------------------------------------------------------------------
__device__ __forceinline__ void align_bar(unsigned* bar, int idx) {
    __syncthreads();
    if (threadIdx.x == 0) {
        __hip_atomic_fetch_add(&bar[idx], 1u, __ATOMIC_RELAXED, __HIP_MEMORY_SCOPE_AGENT);
        while (__hip_atomic_load(&bar[idx], __ATOMIC_RELAXED, __HIP_MEMORY_SCOPE_AGENT) < 96u)
            __builtin_amdgcn_s_sleep(32);
    }
    __syncthreads();
}

// ---------------------------------------------------------------------------
// fp32 tiled GEMM (prologue only)
// ---------------------------------------------------------------------------
__global__ __launch_bounds__(256) void gemm_k(
    const float* __restrict__ A, int lda,
    const float* __restrict__ Bw, int ldb,
    float* __restrict__ C, bf16* __restrict__ Cb, int ldc,
    int K, const float* __restrict__ colBias)
{
    __shared__ float As[16][68];
    __shared__ float Bs[16][68];
    const int tid = threadIdx.x;
    const int tx = tid & 15, ty = tid >> 4;
    const int n0 = blockIdx.y * 64, j0 = blockIdx.x * 64;
    float acc[4][4] = {};
    const int a_kk = tid & 15, a_nn0 = tid >> 4;
    const int b_jj = tid & 63, b_kk0 = tid >> 6;
    for (int k0 = 0; k0 < K; k0 += 16) {
#pragma unroll
        for (int i = 0; i < 4; i++) {
            int nn = a_nn0 + 16 * i;
            As[a_kk][nn] = (k0 + a_kk < K) ? A[(size_t)(n0 + nn) * lda + k0 + a_kk] : 0.f;
        }
#pragma unroll
        for (int i = 0; i < 4; i++) {
            int kk = b_kk0 + 4 * i;
            Bs[kk][b_jj] = (k0 + kk < K) ? Bw[(size_t)(k0 + kk) * ldb + j0 + b_jj] : 0.f;
        }
        __syncthreads();
#pragma unroll
        for (int kk = 0; kk < 16; kk++) {
            float4 av = *(const float4*)&As[kk][ty * 4];
            float4 bv = *(const float4*)&Bs[kk][tx * 4];
            float aa[4] = {av.x, av.y, av.z, av.w};
            float bb[4] = {bv.x, bv.y, bv.z, bv.w};
#pragma unroll
            for (int i = 0; i < 4; i++)
#pragma unroll
                for (int j = 0; j < 4; j++) acc[i][j] += aa[i] * bb[j];
        }
        __syncthreads();
    }
#pragma unroll
    for (int i = 0; i < 4; i++) {
        int n = n0 + ty * 4 + i;
#pragma unroll
        for (int j = 0; j < 4; j++) {
            int jj = j0 + tx * 4 + j;
            float v = acc[i][j];
            if (colBias) v += colBias[jj];
            if (C)  C[(size_t)n * ldc + jj] = v;
            if (Cb) Cb[(size_t)n * ldc + jj] = (bf16)v;
        }
    }
}

// ---------------------------------------------------------------------------
__global__ void pack_k(const float* __restrict__ srcF, const bf16* __restrict__ srcB,
                       int srcRows, int KC, int J, int lds, bf16* __restrict__ dst)
{
    int idx = blockIdx.x * 256 + threadIdx.x;
    int total = (J / 16) * KC * 64;
    if (idx >= total) return;
    int lane = idx & 63;
    int kc = (idx >> 6) % KC;
    int jg = idx / (64 * KC);
    int k0 = kc * 32 + (lane >> 4) * 8;
    int col = jg * 16 + (lane & 15);
    bf16x8 v;
#pragma unroll
    for (int i = 0; i < 8; i++) {
        int r = k0 + i;
        float x = 0.f;
        if (r < srcRows) x = srcF ? srcF[(size_t)r * lds + col] : (float)srcB[(size_t)r * lds + col];
        v[i] = (bf16)x;
    }
    *(bf16x8*)&dst[(size_t)idx * 8] = v;
}

__global__ void weffbt_k(const float* __restrict__ Weff, bf16* __restrict__ Wbt)
{
    int idx = blockIdx.x * 256 + threadIdx.x;
    if (idx >= 256 * 64) return;
    int col = idx >> 6, k = idx & 63;
    Wbt[idx] = (bf16)Weff[k * 256 + col];
}

// ---------------------------------------------------------------------------
__global__ __launch_bounds__(256) void emb_obs_k(
    const float* __restrict__ obs, const float* __restrict__ Wemb,
    const float* __restrict__ bemb, float* __restrict__ emb_obs)
{
    int tid = blockIdx.x * 256 + threadIdx.x;
    if (tid >= OBS_ * B_ * 32) return;
    int r = tid >> 5, e = tid & 31;
    float v = obs[r * 2] * Wemb[e] + obs[r * 2 + 1] * Wemb[32 + e] + bemb[e];
    emb_obs[tid] = fmaxf(v, 0.f);
}

__global__ __launch_bounds__(256) void weff_k(
    const float* __restrict__ Wqkv, const float* __restrict__ bqkv,
    float* __restrict__ Weff)
{
    __shared__ float qrow[512];
    const int r = blockIdx.x;
    const int t = threadIdx.x;
    for (int j = t; j < 512; j += 256)
        qrow[j] = (r < 512) ? Wqkv[(size_t)r * 1536 + j] : bqkv[j];
    __syncthreads();
    const int h = t >> 5, c = t & 31;
    float acc = 0.f;
#pragma unroll 8
    for (int d = 0; d < 64; d++)
        acc += qrow[h * 64 + d] * Wqkv[(size_t)c * 1536 + 512 + h * 64 + d];
    Weff[(size_t)r * 256 + t] = acc;
}

__global__ __launch_bounds__(256) void wov_k(
    const float* __restrict__ Wqkv, const float* __restrict__ Wo,
    bf16* __restrict__ WovCat)
{
    __shared__ float vrow[64];
    const int row = blockIdx.x;
    const int h = row >> 5, c = row & 31;
    const int t = threadIdx.x;
    if (t < 64) vrow[t] = Wqkv[(size_t)c * 1536 + 1024 + h * 64 + t];
    __syncthreads();
    for (int j = t; j < 512; j += 256) {
        float acc = 0.f;
#pragma unroll 8
        for (int d = 0; d < 64; d++)
            acc += vrow[d] * Wo[(size_t)(h * 64 + d) * 512 + j];
        WovCat[(size_t)row * 512 + j] = (bf16)acc;
    }
}

__global__ __launch_bounds__(256) void init_k(
    const float* __restrict__ obs, const float* __restrict__ emb_obs,
    const float* __restrict__ loc, const float* __restrict__ Weff,
    const float* __restrict__ featqp,
    float* __restrict__ A1f, bf16* __restrict__ ecA1b,
    float* __restrict__ small5, float* __restrict__ qp)
{
    __shared__ float A1s[64];
    const int n = blockIdx.x, b = n / 6, m = n % 6, t = threadIdx.x;
    float o0 = obs[(19 * B_ + b) * 2], o1 = obs[(19 * B_ + b) * 2 + 1];
    float g0 = loc[b * 12 + m * 2], g1 = loc[b * 12 + m * 2 + 1];
    if (t < 32) {
        A1s[t] = emb_obs[((size_t)19 * B_ + b) * 32 + t];
    } else if (t < 64) {
        int c = t - 32; float d0 = g0 - o0, d1 = g1 - o1; float tc = 20.f;
        float v;
        if      (c < 8)  v = (c & 1) ? g1 : g0;
        else if (c < 16) v = (c & 1) ? o1 : o0;
        else if (c < 24) v = (c & 1) ? d1 : d0;
        else             v = tc;
        A1s[t] = v;
    }
    if (t < 7) {
        float d0 = g0 - o0, d1 = g1 - o1; float tc = 20.f;
        float v2 = (t==0)?o0:(t==1)?o1:(t==2)?g0:(t==3)?g1:(t==4)?d0:(t==5)?d1:tc;
        small5[n * 8 + t] = v2;
    }
    __syncthreads();
    if (t < 64) {
        A1f[(size_t)n * 64 + t] = A1s[t];
        if (t >= 32) ecA1b[(size_t)n * 288 + 256 + (t - 32)] = (bf16)A1s[t];
    }
    float acc = featqp[(size_t)b * 256 + t];
#pragma unroll 8
    for (int k = 0; k < 64; k++) acc += A1s[k] * Weff[k * 256 + t];
    qp[(size_t)n * 256 + t] = acc;
}

// ===========================================================================
// Persistent row-local megakernel. grid 96 x 1024 (16 waves), 1 block/CU
// via __launch_bounds__(1024,4) -> 128 VGPR cap (R8's spill fix).
// ===========================================================================
__global__ __launch_bounds__(1024, 4) void mega_k(
    float* __restrict__ qp, const float* __restrict__ emb_obs,
    float* __restrict__ emb_gen, bf16* __restrict__ ecA1b,
    const bf16* __restrict__ BpA, const float* __restrict__ featvO,
    float* __restrict__ A1f, const float* __restrict__ feat,
    const float* __restrict__ g1v, const float* __restrict__ b1v,
    float* __restrict__ h1f, const bf16* __restrict__ BpF1,
    const float* __restrict__ bff1, bf16* __restrict__ f1b,
    const bf16* __restrict__ BpF2, const float* __restrict__ bff2,
    const float* __restrict__ g2v, const float* __restrict__ b2v,
    float* __restrict__ small5, const bf16* __restrict__ BpFus,
    const float* __restrict__ feat_fus,
    const float* __restrict__ Wout, const float* __restrict__ bout,
    const float* __restrict__ Wemb, const float* __restrict__ bemb,
    const float* __restrict__ loc, const bf16* __restrict__ WeffBt,
    const float* __restrict__ featqp, float* __restrict__ dout,
    unsigned* __restrict__ bar)
{
    __shared__ __align__(16) unsigned char sm[51200];
    const int tid = threadIdx.x;
    const int bx = blockIdx.x;
    const int n0 = bx * 16;
    const int wv = tid >> 6, lane = tid & 63, quad = lane >> 4, m15 = lane & 15;

    float* aFs  = (float*)sm;
    float* stat = (float*)(sm + 33024);
    bf16*  h1fr = (bf16*)(sm + 33152);
    bf16*  h2fr = (bf16*)(sm + 33216);
    float* A1ss = (float*)(sm + 33216);

    for (int s = 0; s < HOR_; s++) {
        const int t = OBS_ + s;
        // ---------------- P1: attention (16 n, 4 concurrent x 4 iters) --------
        {
            const int grp = tid >> 8, t8 = tid & 255;
            float* qps  = (float*)(sm + grp * 8704);
            float* embs = qps + 256;
            float* ats  = embs + 1650;
            for (int it = 0; it < 4; it++) {
                const int n = n0 + it * 4 + grp;
                const int b = n / 6;
                qps[t8] = qp[(size_t)n * 256 + t8];
                for (int idx = t8; idx < t * 32; idx += 256) {
                    int l = idx >> 5, c = idx & 31;
                    embs[l * 33 + c] = (l < OBS_) ? emb_obs[((size_t)l * B_ + b) * 32 + c]
                                                  : emb_gen[((size_t)(l - OBS_) * N_ + n) * 32 + c];
                }
                __syncthreads();
                const int w4 = t8 >> 6;
#pragma unroll
                for (int hh = 0; hh < 2; hh++) {
                    const int h = w4 * 2 + hh;
                    float sc = -1e30f;
                    if (lane < t) {
                        float s_ = 0.f;
#pragma unroll 8
                        for (int c = 0; c < 32; c++) s_ += embs[lane * 33 + c] * qps[h * 32 + c];
                        sc = s_ * 0.125f;
                    }
                    float mx = sc;
#pragma unroll
                    for (int o = 32; o > 0; o >>= 1) mx = fmaxf(mx, __shfl_xor(mx, o, 64));
                    float e = (lane < t) ? __expf(sc - mx) : 0.f;
                    float smv = e;
#pragma unroll
                    for (int o = 32; o > 0; o >>= 1) smv += __shfl_xor(smv, o, 64);
                    ats[w4 * 64 + lane] = e / smv;
                    if (lane < 32) {
                        float ec = 0.f;
                        for (int l = 0; l < t; l++) ec += ats[w4 * 64 + l] * embs[l * 33 + lane];
                        ecA1b[(size_t)n * 288 + h * 32 + lane] = (bf16)ec;
                    }
                }
                __syncthreads();
            }
        }
        // ---------------- P2: aGEMM (K=288) + residual -> aFs (LDS) -----------
        // All 18 B-frags hoisted (72 VGPR); A streamed (compiler pipelines).
        {
            const int jgA = wv * 2, jgB = jgA + 1;
            const bf16* Ar = &ecA1b[(size_t)(n0 + m15) * 288 + quad * 8];
            const bf16* B0 = &BpA[((size_t)jgA * 9 * 64 + lane) * 8];
            const bf16* B1 = &BpA[((size_t)jgB * 9 * 64 + lane) * 8];
            bf16x8 b0_[9], b1_[9];
#pragma unroll
            for (int kc = 0; kc < 9; kc++) {
                b0_[kc] = *(const bf16x8*)&B0[(size_t)kc * 512];
                b1_[kc] = *(const bf16x8*)&B1[(size_t)kc * 512];
            }
            f32x4 a0 = {}, a1 = {};
#pragma unroll
            for (int kc = 0; kc < 9; kc++) {
                bf16x8 af = *(const bf16x8*)&Ar[kc * 32];
                a0 = MF(af, b0_[kc], a0); a1 = MF(af, b1_[kc], a1);
            }
#pragma unroll
            for (int g = 0; g < 2; g++) {
                f32x4 ac = g ? a1 : a0;
                int j = (jgA + g) * 16 + m15;
#pragma unroll
                for (int r = 0; r < 4; r++) {
                    int row = quad * 4 + r, n = n0 + row, b = n / 6;
                    float x = (j < 64) ? A1f[(size_t)n * 64 + j] : feat[(size_t)b * 448 + (j - 64)];
                    aFs[row * 516 + j] = ac[r] + featvO[(size_t)b * 512 + j] + x;
                }
            }
            __syncthreads();
        }
        // ---------------- P3a: LN1 stats (wave per row) -----------------------
        {
            const int row = wv;
            const float* base = &aFs[row * 516 + lane * 8];
            float s_ = 0.f, sq = 0.f;
#pragma unroll
            for (int i = 0; i < 8; i++) { float v = base[i]; s_ += v; sq += v * v; }
#pragma unroll
            for (int o = 32; o > 0; o >>= 1) { s_ += __shfl_xor(s_, o, 64); sq += __shfl_xor(sq, o, 64); }
            if (lane == 0) {
                float mu = s_ * (1.f / 512.f);
                float var = sq * (1.f / 512.f) - mu * mu;
                stat[row] = mu; stat[16 + row] = rsqrtf(var + 1e-5f);
            }
            __syncthreads();
        }
        // ---------------- P3b: normalize -> h1 frags (LDS) + h1f (global) -----
        {
            const int kc = tid >> 6;
            const int row = m15;
            const int k0 = kc * 32 + quad * 8;
            const float* src = &aFs[row * 516 + k0];
            float mu = stat[row], rs = stat[16 + row];
            float fo[8]; bf16x8 v8;
#pragma unroll
            for (int i = 0; i < 8; i++) {
                fo[i] = (src[i] - mu) * rs * g1v[k0 + i] + b1v[k0 + i];
                v8[i] = (bf16)fo[i];
            }
            *(bf16x8*)&h1fr[((size_t)kc * 64 + lane) * 8] = v8;
            float4 o0 = {fo[0], fo[1], fo[2], fo[3]}, o1 = {fo[4], fo[5], fo[6], fo[7]};
            *(float4*)&h1f[(size_t)(n0 + row) * 512 + k0]     = o0;
            *(float4*)&h1f[(size_t)(n0 + row) * 512 + k0 + 4] = o1;
            __syncthreads();
        }
        align_bar(bar, s * 2);
        // ---------------- P3c: FF1 (K=512,J=2048) + transpose -> f1b frags ----
        // 2x4-deep double buffer per stream: 8-16 loads in flight.
        {
            bf16* scr = (bf16*)(sm + wv * 1024);
#pragma unroll
            for (int pair = 0; pair < 4; pair++) {
                const int jgA = wv * 8 + pair * 2, jgB = jgA + 1;
                const bf16* B0 = &BpF1[((size_t)jgA * 16 * 64 + lane) * 8];
                const bf16* B1 = &BpF1[((size_t)jgB * 16 * 64 + lane) * 8];
                bf16x8 b0_[2][4], b1_[2][4];
#pragma unroll
                for (int i = 0; i < 4; i++) {
                    b0_[0][i] = *(const bf16x8*)&B0[(size_t)i * 512];
                    b1_[0][i] = *(const bf16x8*)&B1[(size_t)i * 512];
                }
                f32x4 a0 = {}, a1 = {};
#pragma unroll
                for (int c = 0; c < 4; c++) {
                    const int cur = c & 1, nxt = cur ^ 1;
                    if (c < 3) {
#pragma unroll
                        for (int i = 0; i < 4; i++) {
                            b0_[nxt][i] = *(const bf16x8*)&B0[(size_t)((c + 1) * 4 + i) * 512];
                            b1_[nxt][i] = *(const bf16x8*)&B1[(size_t)((c + 1) * 4 + i) * 512];
                        }
                    }
#pragma unroll
                    for (int i = 0; i < 4; i++) {
                        bf16x8 af = *(const bf16x8*)&h1fr[((size_t)(c * 4 + i) * 64 + lane) * 8];
                        a0 = MF(af, b0_[cur][i], a0); a1 = MF(af, b1_[cur][i], a1);
                    }
                }
                float cb0 = bff1[jgA * 16 + m15], cb1 = bff1[jgB * 16 + m15];
#pragma unroll
                for (int r = 0; r < 4; r++) {
                    int row = quad * 4 + r;
                    scr[row * 32 + m15]      = (bf16)fmaxf(a0[r] + cb0, 0.f);
                    scr[row * 32 + 16 + m15] = (bf16)fmaxf(a1[r] + cb1, 0.f);
                }
                __syncthreads();
                const int kc2 = wv * 4 + pair;
                bf16x8 fr = *(const bf16x8*)&scr[m15 * 32 + quad * 8];
                *(bf16x8*)&f1b[((size_t)(bx * 64 + kc2) * 64 + lane) * 8] = fr;
                __syncthreads();
            }
        }
        align_bar(bar, s * 2 + 1);
        // ---------------- P4: FF2 (K=2048) + bias + h1f residual -> aFs -------
        // B-streams 2x4-deep double-buffered (16 frags); A per-chunk hoist.
        {
            const int jgA = wv * 2, jgB = jgA + 1;
            const bf16* fA = &f1b[(size_t)bx * 64 * 64 * 8];
            const bf16* B0 = &BpF2[((size_t)jgA * 64 * 64 + lane) * 8];
            const bf16* B1 = &BpF2[((size_t)jgB * 64 * 64 + lane) * 8];
            bf16x8 b0_[2][4], b1_[2][4];
#pragma unroll
            for (int i = 0; i < 4; i++) {
                b0_[0][i] = *(const bf16x8*)&B0[(size_t)i * 512];
                b1_[0][i] = *(const bf16x8*)&B1[(size_t)i * 512];
            }
            f32x4 a0 = {}, a1 = {};
#pragma unroll
            for (int c = 0; c < 16; c++) {
                const int cur = c & 1, nxt = cur ^ 1;
                if (c < 15) {
#pragma unroll
                    for (int i = 0; i < 4; i++) {
                        b0_[nxt][i] = *(const bf16x8*)&B0[(size_t)((c + 1) * 4 + i) * 512];
                        b1_[nxt][i] = *(const bf16x8*)&B1[(size_t)((c + 1) * 4 + i) * 512];
                    }
                }
                bf16x8 af_[4];
#pragma unroll
                for (int i = 0; i < 4; i++)
                    af_[i] = *(const bf16x8*)&fA[((size_t)(c * 4 + i) * 64 + lane) * 8];
#pragma unroll
                for (int i = 0; i < 4; i++) {
                    a0 = MF(af_[i], b0_[cur][i], a0);
                    a1 = MF(af_[i], b1_[cur][i], a1);
                }
            }
#pragma unroll
            for (int g = 0; g < 2; g++) {
                f32x4 ac = g ? a1 : a0;
                int j = (jgA + g) * 16 + m15;
                float cb = bff2[j];
#pragma unroll
                for (int r = 0; r < 4; r++) {
                    int row = quad * 4 + r;
                    aFs[row * 516 + j] = ac[r] + cb + h1f[(size_t)(n0 + row) * 512 + j];
                }
            }
            __syncthreads();
        }
        // ---------------- P5a: LN2 stats ----------------
        {
            const int row = wv;
            const float* base = &aFs[row * 516 + lane * 8];
            float s_ = 0.f, sq = 0.f;
#pragma unroll
            for (int i = 0; i < 8; i++) { float v = base[i]; s_ += v; sq += v * v; }
#pragma unroll
            for (int o = 32; o > 0; o >>= 1) { s_ += __shfl_xor(s_, o, 64); sq += __shfl_xor(sq, o, 64); }
            if (lane == 0) {
                float mu = s_ * (1.f / 512.f);
                float var = sq * (1.f / 512.f) - mu * mu;
                stat[row] = mu; stat[16 + row] = rsqrtf(var + 1e-5f);
            }
            __syncthreads();
        }
        // ---------------- P5b: h2 frags (K=544: LN2 | small5 | 0) -------------
        {
#pragma unroll
            for (int i = 0; i < 2; i++) {
                int q = tid + i * 1024;
                if (q < 1088) {
                    int ql = q & 63, kc = q >> 6;
                    int row = ql & 15, qq = ql >> 4;
                    int k0 = kc * 32 + qq * 8;
                    float mu = stat[row], rs = stat[16 + row];
                    bf16x8 v8;
#pragma unroll
                    for (int ii = 0; ii < 8; ii++) {
                        int k = k0 + ii;
                        float val;
                        if (k < 512)      val = (aFs[row * 516 + k] - mu) * rs * g2v[k] + b2v[k];
                        else if (k < 519) val = small5[(size_t)(n0 + row) * 8 + (k - 512)];
                        else              val = 0.f;
                        v8[ii] = (bf16)val;
                    }
                    *(bf16x8*)&h2fr[((size_t)kc * 64 + ql) * 8] = v8;
                }
            }
            __syncthreads();
        }
        // ---------------- P5c: fus GEMM (K=544,J=448), two full-hoist passes --
        {
            float* fuss = (float*)sm;
            // pass 1: j-group = wv (all 16 waves)
            {
                const bf16* B0 = &BpFus[((size_t)wv * 17 * 64 + lane) * 8];
                bf16x8 b0_[17];
#pragma unroll
                for (int kc = 0; kc < 17; kc++) b0_[kc] = *(const bf16x8*)&B0[(size_t)kc * 512];
                f32x4 a0 = {};
#pragma unroll
                for (int kc = 0; kc < 17; kc++) {
                    bf16x8 af = *(const bf16x8*)&h2fr[((size_t)kc * 64 + lane) * 8];
                    a0 = MF(af, b0_[kc], a0);
                }
                int j = wv * 16 + m15;
#pragma unroll
                for (int r = 0; r < 4; r++) {
                    int row = quad * 4 + r, n = n0 + row, b = n / 6;
                    fuss[row * 452 + j] = a0[r] + feat_fus[(size_t)b * 448 + j];
                }
            }
            // pass 2: j-group = 16 + wv (waves 0..11)
            if (wv < 12) {
                const bf16* B1 = &BpFus[((size_t)(16 + wv) * 17 * 64 + lane) * 8];
                bf16x8 b1_[17];
#pragma unroll
                for (int kc = 0; kc < 17; kc++) b1_[kc] = *(const bf16x8*)&B1[(size_t)kc * 512];
                f32x4 a1 = {};
#pragma unroll
                for (int kc = 0; kc < 17; kc++) {
                    bf16x8 af = *(const bf16x8*)&h2fr[((size_t)kc * 64 + lane) * 8];
                    a1 = MF(af, b1_[kc], a1);
                }
                int j = (16 + wv) * 16 + m15;
#pragma unroll
                for (int r = 0; r < 4; r++) {
                    int row = quad * 4 + r, n = n0 + row, b = n / 6;
                    fuss[row * 452 + j] = a1[r] + feat_fus[(size_t)b * 448 + j];
                }
            }
            __syncthreads();
        }
        // ---------------- P6: out-proj + next-state + qp (wave per row) -------
        {
            const int row = wv, n = n0 + row, b = n / 6, m = n % 6;
            const float* fr = (const float*)sm + row * 452;
            float p0 = 0.f, p1 = 0.f;
#pragma unroll
            for (int i = 0; i < 7; i++) {
                int j = lane + i * 64;
                float f = fr[j];
                p0 += f * Wout[j * 2];
                p1 += f * Wout[j * 2 + 1];
            }
#pragma unroll
            for (int o = 32; o > 0; o >>= 1) { p0 += __shfl_xor(p0, o, 64); p1 += __shfl_xor(p1, o, 64); }
            float o0 = p0 + bout[0], o1 = p1 + bout[1];
            if (lane == 0) {
                dout[(size_t)b * 360 + m * 60 + s * 2]     = o0;
                dout[(size_t)b * 360 + m * 60 + s * 2 + 1] = o1;
            }
            float g0 = loc[b * 12 + m * 2], g1 = loc[b * 12 + m * 2 + 1];
            float d0 = g0 - o0, d1 = g1 - o1;
            float tc = (float)(OBS_ + s + 1);
            float v;
            if (lane < 32) {
                v = fmaxf(o0 * Wemb[lane] + o1 * Wemb[32 + lane] + bemb[lane], 0.f);
                emb_gen[((size_t)s * N_ + n) * 32 + lane] = v;
            } else {
                int c = lane - 32;
                if      (c < 8)  v = (c & 1) ? g1 : g0;
                else if (c < 16) v = (c & 1) ? o1 : o0;
                else if (c < 24) v = (c & 1) ? d1 : d0;
                else             v = tc;
                ecA1b[(size_t)n * 288 + 256 + c] = (bf16)v;
            }
            A1ss[row * 64 + lane] = v;
            A1f[(size_t)n * 64 + lane] = v;
            if (lane < 7) {
                float v2 = (lane==0)?o0:(lane==1)?o1:(lane==2)?g0:(lane==3)?g1:(lane==4)?d0:(lane==5)?d1:tc;
                small5[(size_t)n * 8 + lane] = v2;
            }
            __syncthreads();
#pragma unroll
            for (int i = 0; i < 4; i++) {
                int col = lane + i * 64;
                const bf16* wp = &WeffBt[(size_t)col * 64];
                float acc = featqp[(size_t)b * 256 + col];
#pragma unroll
                for (int k8 = 0; k8 < 8; k8++) {
                    bf16x8 w8 = *(const bf16x8*)&wp[k8 * 8];
#pragma unroll
                    for (int k = 0; k < 8; k++)
                        acc += A1ss[row * 64 + k8 * 8 + k] * (float)w8[k];
                }
                qp[(size_t)n * 256 + col] = acc;
            }
            __syncthreads();
        }
    }
}

// ---------------------------------------------------------------------------
extern "C" void kernel_launch(void* const* d_in, const int* in_sizes, int n_in,
                              void* d_out_, int out_size, void* d_ws, size_t ws_size,
                              hipStream_t stream) {
    (void)in_sizes; (void)n_in; (void)out_size; (void)ws_size;
    const float* feat  = (const float*)d_in[0];
    const float* loc   = (const float*)d_in[1];
    const float* obs   = (const float*)d_in[2];
    const float* W_emb = (const float*)d_in[3];
    const float* b_emb = (const float*)d_in[4];
    const float* W_qkv = (const float*)d_in[5];
    const float* b_qkv = (const float*)d_in[6];
    const float* W_o   = (const float*)d_in[7];
    const float* b_o   = (const float*)d_in[8];
    const float* W_ff1 = (const float*)d_in[9];
    const float* b_ff1 = (const float*)d_in[10];
    const float* W_ff2 = (const float*)d_in[11];
    const float* b_ff2 = (const float*)d_in[12];
    const float* ln1_g = (const float*)d_in[13];
    const float* ln1_b = (const float*)d_in[14];
    const float* ln2_g = (const float*)d_in[15];
    const float* ln2_b = (const float*)d_in[16];
    const float* W_fus = (const float*)d_in[17];
    const float* b_fus = (const float*)d_in[18];
    const float* W_out = (const float*)d_in[19];
    const float* b_out = (const float*)d_in[20];
    float* dout = (float*)d_out_;

    unsigned* bar = (unsigned*)d_ws;               // 128 alignment slots
    float* ws = (float*)d_ws + 128;
    float* Weff     = ws; ws += 513 * 256;
    float* featqp   = ws; ws += 256 * 256;
    float* featv    = ws; ws += 256 * 512;
    float* featvO   = ws; ws += 256 * 512;
    float* feat_fus = ws; ws += 256 * 448;
    float* emb_obs  = ws; ws += OBS_ * B_ * 32;
    float* emb_gen  = ws; ws += HOR_ * N_ * 32;
    float* qp       = ws; ws += (size_t)N_ * 256;
    float* A1f      = ws; ws += (size_t)N_ * 64;
    float* small5   = ws; ws += (size_t)N_ * 8;
    float* h1f      = ws; ws += (size_t)N_ * 512;
    bf16* WovCat = (bf16*)ws; ws += (320 * 512) / 2;
    bf16* BpA    = (bf16*)ws; ws += (32 * 9 * 512) / 2;
    bf16* BpF1   = (bf16*)ws; ws += (128 * 16 * 512) / 2;
    bf16* BpF2   = (bf16*)ws; ws += (32 * 64 * 512) / 2;
    bf16* BpFus  = (bf16*)ws; ws += (28 * 17 * 512) / 2;
    bf16* WeffBt = (bf16*)ws; ws += (256 * 64) / 2;
    bf16* ecA1b  = (bf16*)ws; ws += ((size_t)N_ * 288) / 2;
    bf16* f1b    = (bf16*)ws; ws += ((size_t)N_ * 2048) / 2;

    hipMemsetAsync(bar, 0, 128 * sizeof(unsigned), stream);

    // ---- prologue ----
    emb_obs_k<<<dim3(640), dim3(256), 0, stream>>>(obs, W_emb, b_emb, emb_obs);
    weff_k<<<dim3(513), dim3(256), 0, stream>>>(W_qkv, b_qkv, Weff);
    gemm_k<<<dim3(4, 4), dim3(256), 0, stream>>>(feat, 448, Weff + 64 * 256, 256,
        featqp, nullptr, 256, 448, Weff + 512 * 256);
    weffbt_k<<<dim3(64), dim3(256), 0, stream>>>(Weff, WeffBt);
    wov_k<<<dim3(256), dim3(256), 0, stream>>>(W_qkv, W_o, WovCat);
    gemm_k<<<dim3(8, 4), dim3(256), 0, stream>>>(feat, 448, W_qkv + 64 * 1536 + 1024, 1536,
        featv, nullptr, 512, 448, b_qkv + 1024);
    gemm_k<<<dim3(8, 4), dim3(256), 0, stream>>>(featv, 512, W_o, 512,
        featvO, nullptr, 512, 512, b_o);
    gemm_k<<<dim3(8, 1), dim3(256), 0, stream>>>(W_qkv + 32 * 1536 + 1024, 1536, W_o, 512,
        featv, WovCat + 256 * 512, 512, 512, nullptr);
    gemm_k<<<dim3(7, 4), dim3(256), 0, stream>>>(feat, 448, W_fus + 519 * 448, 448,
        feat_fus, nullptr, 448, 448, b_fus);
    pack_k<<<dim3(72),  dim3(256), 0, stream>>>(nullptr, WovCat, 288, 9,  512,  512,  BpA);
    pack_k<<<dim3(512), dim3(256), 0, stream>>>(W_ff1, nullptr, 512, 16, 2048, 2048, BpF1);
    pack_k<<<dim3(512), dim3(256), 0, stream>>>(W_ff2, nullptr, 2048, 64, 512, 512,  BpF2);
    pack_k<<<dim3(120), dim3(256), 0, stream>>>(W_fus, nullptr, 519, 17, 448,  448,  BpFus);
    init_k<<<dim3(N_), dim3(256), 0, stream>>>(obs, emb_obs, loc, Weff, featqp,
        A1f, ecA1b, small5, qp);

    // ---- persistent row-local 30-step megakernel ----
    mega_k<<<dim3(96), dim3(1024), 0, stream>>>(
        qp, emb_obs, emb_gen, ecA1b, BpA, featvO, A1f, feat,
        ln1_g, ln1_b, h1f, BpF1, b_ff1, f1b, BpF2, b_ff2,
        ln2_g, ln2_b, small5, BpFus, feat_fus,
        W_out, b_out, W_emb, b_emb, loc, WeffBt, featqp, dout, bar);
}

// Round 10
// 3318.800 us; speedup vs baseline: 3.8385x; 3.8385x over previous
//
#include <hip/hip_runtime.h>
#include <math.h>

#define B_   256
#define N_   1536
#define OBS_ 20
#define HOR_ 30

typedef __bf16 bf16;
typedef bf16  bf16x8 __attribute__((ext_vector_type(8)));
typedef float f32x4  __attribute__((ext_vector_type(4)));

__device__ __forceinline__ f32x4 MF(bf16x8 a, bf16x8 b, f32x4 c) {
    return __builtin_amdgcn_mfma_f32_16x16x32_bf16(a, b, c, 0, 0, 0);
}

// ---------------------------------------------------------------------------
// fp32 tiled GEMM (prologue only)
// ---------------------------------------------------------------------------
__global__ __launch_bounds__(256) void gemm_k(
    const float* __restrict__ A, int lda,
    const float* __restrict__ Bw, int ldb,
    float* __restrict__ C, bf16* __restrict__ Cb, int ldc,
    int K, const float* __restrict__ colBias)
{
    __shared__ float As[16][68];
    __shared__ float Bs[16][68];
    const int tid = threadIdx.x;
    const int tx = tid & 15, ty = tid >> 4;
    const int n0 = blockIdx.y * 64, j0 = blockIdx.x * 64;
    float acc[4][4] = {};
    const int a_kk = tid & 15, a_nn0 = tid >> 4;
    const int b_jj = tid & 63, b_kk0 = tid >> 6;
    for (int k0 = 0; k0 < K; k0 += 16) {
#pragma unroll
        for (int i = 0; i < 4; i++) {
            int nn = a_nn0 + 16 * i;
            As[a_kk][nn] = (k0 + a_kk < K) ? A[(size_t)(n0 + nn) * lda + k0 + a_kk] : 0.f;
        }
#pragma unroll
        for (int i = 0; i < 4; i++) {
            int kk = b_kk0 + 4 * i;
            Bs[kk][b_jj] = (k0 + kk < K) ? Bw[(size_t)(k0 + kk) * ldb + j0 + b_jj] : 0.f;
        }
        __syncthreads();
#pragma unroll
        for (int kk = 0; kk < 16; kk++) {
            float4 av = *(const float4*)&As[kk][ty * 4];
            float4 bv = *(const float4*)&Bs[kk][tx * 4];
            float aa[4] = {av.x, av.y, av.z, av.w};
            float bb[4] = {bv.x, bv.y, bv.z, bv.w};
#pragma unroll
            for (int i = 0; i < 4; i++)
#pragma unroll
                for (int j = 0; j < 4; j++) acc[i][j] += aa[i] * bb[j];
        }
        __syncthreads();
    }
#pragma unroll
    for (int i = 0; i < 4; i++) {
        int n = n0 + ty * 4 + i;
#pragma unroll
        for (int j = 0; j < 4; j++) {
            int jj = j0 + tx * 4 + j;
            float v = acc[i][j];
            if (colBias) v += colBias[jj];
            if (C)  C[(size_t)n * ldc + jj] = v;
            if (Cb) Cb[(size_t)n * ldc + jj] = (bf16)v;
        }
    }
}

// ---------------------------------------------------------------------------
__global__ void pack_k(const float* __restrict__ srcF, const bf16* __restrict__ srcB,
                       int srcRows, int KC, int J, int lds, bf16* __restrict__ dst)
{
    int idx = blockIdx.x * 256 + threadIdx.x;
    int total = (J / 16) * KC * 64;
    if (idx >= total) return;
    int lane = idx & 63;
    int kc = (idx >> 6) % KC;
    int jg = idx / (64 * KC);
    int k0 = kc * 32 + (lane >> 4) * 8;
    int col = jg * 16 + (lane & 15);
    bf16x8 v;
#pragma unroll
    for (int i = 0; i < 8; i++) {
        int r = k0 + i;
        float x = 0.f;
        if (r < srcRows) x = srcF ? srcF[(size_t)r * lds + col] : (float)srcB[(size_t)r * lds + col];
        v[i] = (bf16)x;
    }
    *(bf16x8*)&dst[(size_t)idx * 8] = v;
}

// ---------------------------------------------------------------------------
__global__ __launch_bounds__(256) void emb_obs_k(
    const float* __restrict__ obs, const float* __restrict__ Wemb,
    const float* __restrict__ bemb, float* __restrict__ emb_obs)
{
    int tid = blockIdx.x * 256 + threadIdx.x;
    if (tid >= OBS_ * B_ * 32) return;
    int r = tid >> 5, e = tid & 31;
    float v = obs[r * 2] * Wemb[e] + obs[r * 2 + 1] * Wemb[32 + e] + bemb[e];
    emb_obs[tid] = fmaxf(v, 0.f);
}

__global__ __launch_bounds__(256) void weff_k(
    const float* __restrict__ Wqkv, const float* __restrict__ bqkv,
    float* __restrict__ Weff)
{
    __shared__ float qrow[512];
    const int r = blockIdx.x;
    const int t = threadIdx.x;
    for (int j = t; j < 512; j += 256)
        qrow[j] = (r < 512) ? Wqkv[(size_t)r * 1536 + j] : bqkv[j];
    __syncthreads();
    const int h = t >> 5, c = t & 31;
    float acc = 0.f;
#pragma unroll 8
    for (int d = 0; d < 64; d++)
        acc += qrow[h * 64 + d] * Wqkv[(size_t)c * 1536 + 512 + h * 64 + d];
    Weff[(size_t)r * 256 + t] = acc;
}

__global__ __launch_bounds__(256) void wov_k(
    const float* __restrict__ Wqkv, const float* __restrict__ Wo,
    bf16* __restrict__ WovCat)
{
    __shared__ float vrow[64];
    const int row = blockIdx.x;
    const int h = row >> 5, c = row & 31;
    const int t = threadIdx.x;
    if (t < 64) vrow[t] = Wqkv[(size_t)c * 1536 + 1024 + h * 64 + t];
    __syncthreads();
    for (int j = t; j < 512; j += 256) {
        float acc = 0.f;
#pragma unroll 8
        for (int d = 0; d < 64; d++)
            acc += vrow[d] * Wo[(size_t)(h * 64 + d) * 512 + j];
        WovCat[(size_t)row * 512 + j] = (bf16)acc;
    }
}

__global__ __launch_bounds__(256) void init_k(
    const float* __restrict__ obs, const float* __restrict__ emb_obs,
    const float* __restrict__ loc, const float* __restrict__ Weff,
    const float* __restrict__ featqp,
    float* __restrict__ A1f, bf16* __restrict__ ecA1b,
    float* __restrict__ small5, float* __restrict__ qp)
{
    __shared__ float A1s[64];
    const int n = blockIdx.x, b = n / 6, m = n % 6, t = threadIdx.x;
    float o0 = obs[(19 * B_ + b) * 2], o1 = obs[(19 * B_ + b) * 2 + 1];
    float g0 = loc[b * 12 + m * 2], g1 = loc[b * 12 + m * 2 + 1];
    if (t < 32) {
        A1s[t] = emb_obs[((size_t)19 * B_ + b) * 32 + t];
    } else if (t < 64) {
        int c = t - 32; float d0 = g0 - o0, d1 = g1 - o1; float tc = 20.f;
        float v;
        if      (c < 8)  v = (c & 1) ? g1 : g0;
        else if (c < 16) v = (c & 1) ? o1 : o0;
        else if (c < 24) v = (c & 1) ? d1 : d0;
        else             v = tc;
        A1s[t] = v;
    }
    if (t < 7) {
        float d0 = g0 - o0, d1 = g1 - o1; float tc = 20.f;
        float v2 = (t==0)?o0:(t==1)?o1:(t==2)?g0:(t==3)?g1:(t==4)?d0:(t==5)?d1:tc;
        small5[n * 8 + t] = v2;
    }
    __syncthreads();
    if (t < 64) {
        A1f[(size_t)n * 64 + t] = A1s[t];
        if (t >= 32) ecA1b[(size_t)n * 288 + 256 + (t - 32)] = (bf16)A1s[t];
    }
    float acc = featqp[(size_t)b * 256 + t];
#pragma unroll 8
    for (int k = 0; k < 64; k++) acc += A1s[k] * Weff[k * 256 + t];
    qp[(size_t)n * 256 + t] = acc;
}

// ---------------------------------------------------------------------------
// Attention (R5 verbatim): ec -> ecA1b[:,0:256] bf16. grid N x 256.
// ---------------------------------------------------------------------------
__global__ __launch_bounds__(256) void attn_k(
    const float* __restrict__ qp, const float* __restrict__ emb_obs,
    const float* __restrict__ emb_gen, bf16* __restrict__ ecA1b, int t)
{
    __shared__ float qp_s[256];
    __shared__ float emb_s[50 * 33];
    __shared__ float at_s[4][64];
    const int n = blockIdx.x, b = n / 6, tid = threadIdx.x;
    qp_s[tid] = qp[(size_t)n * 256 + tid];
    for (int idx = tid; idx < t * 32; idx += 256) {
        int l = idx >> 5, c = idx & 31;
        emb_s[l * 33 + c] = (l < OBS_) ? emb_obs[((size_t)l * B_ + b) * 32 + c]
                                       : emb_gen[((size_t)(l - OBS_) * N_ + n) * 32 + c];
    }
    __syncthreads();
    const int w = tid >> 6, lane = tid & 63;
#pragma unroll
    for (int hh = 0; hh < 2; hh++) {
        const int h = w * 2 + hh;
        float sc = -1e30f;
        if (lane < t) {
            float s_ = 0.f;
#pragma unroll 8
            for (int c = 0; c < 32; c++) s_ += emb_s[lane * 33 + c] * qp_s[h * 32 + c];
            sc = s_ * 0.125f;
        }
        float mx = sc;
#pragma unroll
        for (int o = 32; o > 0; o >>= 1) mx = fmaxf(mx, __shfl_xor(mx, o, 64));
        float e = (lane < t) ? __expf(sc - mx) : 0.f;
        float sm = e;
#pragma unroll
        for (int o = 32; o > 0; o >>= 1) sm += __shfl_xor(sm, o, 64);
        at_s[w][lane] = e / sm;
        if (lane < 32) {
            float ec = 0.f;
            for (int l = 0; l < t; l++) ec += at_s[w][l] * emb_s[l * 33 + lane];
            ecA1b[(size_t)n * 288 + h * 32 + lane] = (bf16)ec;
        }
    }
}

// ---------------------------------------------------------------------------
// aGEMM: aF[n,j] = [ec|extras]@Wov + featvO[b][j] + x_last(n,j).  K=288.
// Tile 32 rows x 64 cols (R5 fgemm layout); grid (8, 48).
// ---------------------------------------------------------------------------
__global__ __launch_bounds__(256) void agemm_k(
    const bf16* __restrict__ A, const bf16* __restrict__ Bp,
    const float* __restrict__ featvO, const float* __restrict__ A1f,
    const float* __restrict__ feat, float* __restrict__ aF)
{
    const int n0 = blockIdx.y * 32;
    const int j0g = blockIdx.x * 4;
    const int tid = threadIdx.x;
    const int w = tid >> 6, lane = tid & 63;
    const int quad = lane >> 4, m15 = lane & 15;
    const int r0 = (w & 1) * 16;
    const int cg = (w >> 1) * 2;
    const bf16* Arow = &A[(size_t)(n0 + r0 + m15) * 288 + quad * 8];
    const bf16* B0 = &Bp[((size_t)(j0g + cg) * 9 * 64 + lane) * 8];
    const bf16* B1 = &Bp[((size_t)(j0g + cg + 1) * 9 * 64 + lane) * 8];
    f32x4 a0 = {}, a1 = {};
#pragma unroll
    for (int kc = 0; kc < 9; kc++) {
        bf16x8 af = *(const bf16x8*)&Arow[kc * 32];
        bf16x8 b0 = *(const bf16x8*)&B0[(size_t)kc * 512];
        bf16x8 b1 = *(const bf16x8*)&B1[(size_t)kc * 512];
        a0 = MF(af, b0, a0); a1 = MF(af, b1, a1);
    }
#pragma unroll
    for (int g = 0; g < 2; g++) {
        f32x4 ac = g ? a1 : a0;
        int j = (j0g + cg + g) * 16 + m15;
#pragma unroll
        for (int r = 0; r < 4; r++) {
            int n = n0 + r0 + quad * 4 + r, b = n / 6;
            float x = (j < 64) ? A1f[(size_t)n * 64 + j] : feat[(size_t)b * 448 + (j - 64)];
            aF[(size_t)n * 512 + j] = ac[r] + featvO[(size_t)b * 512 + j] + x;
        }
    }
}

// ---------------------------------------------------------------------------
// FF1 + fused LN1: reads aF rows (K-input), computes LN1 per row in-block,
// GEMM vs BpF1 column slice -> f1b (bf16, relu). jb==0 blocks also write h1f.
// Block: 32 rows x 128 cols. grid (16, 48).
// ---------------------------------------------------------------------------
__global__ __launch_bounds__(256) void ff1ln_k(
    const float* __restrict__ aF, const bf16* __restrict__ Bp,
    const float* __restrict__ g1, const float* __restrict__ b1,
    const float* __restrict__ bff1,
    bf16* __restrict__ f1b, float* __restrict__ h1f)
{
    __shared__ bf16 frag[2 * 16 * 64 * 8];    // 32 KB
    __shared__ float mu_s[32], rs_s[32];
    const int n0 = blockIdx.y * 32;
    const int jb = blockIdx.x;
    const int tid = threadIdx.x;
    const int w = tid >> 6, lane = tid & 63;
    const int quad = lane >> 4, m15 = lane & 15;

    // LN1 stats: 8 threads per row
    {
        int row = tid >> 3, part = tid & 7;
        const float* base = &aF[(size_t)(n0 + row) * 512 + part * 64];
        float s = 0.f, sq = 0.f;
#pragma unroll
        for (int i = 0; i < 16; i++) {
            float4 v = *(const float4*)&base[i * 4];
            s += v.x + v.y + v.z + v.w;
            sq += v.x * v.x + v.y * v.y + v.z * v.z + v.w * v.w;
        }
#pragma unroll
        for (int o = 1; o < 8; o <<= 1) { s += __shfl_xor(s, o, 64); sq += __shfl_xor(sq, o, 64); }
        if (part == 0) {
            float mu = s * (1.f / 512.f);
            float var = sq * (1.f / 512.f) - mu * mu;
            mu_s[row] = mu; rs_s[row] = rsqrtf(var + 1e-5f);
        }
    }
    __syncthreads();
    // normalize -> frag LDS (+ h1f when jb==0)
#pragma unroll
    for (int it = 0; it < 8; it++) {
        int q = tid + it * 256;
        int ln = q & 63, kc = (q >> 6) & 15, rg = q >> 10;
        int row = rg * 16 + (ln & 15), k0 = kc * 32 + (ln >> 4) * 8;
        const float* src = &aF[(size_t)(n0 + row) * 512 + k0];
        float mu = mu_s[row], rs = rs_s[row];
        float fo[8]; bf16x8 v8;
#pragma unroll
        for (int i = 0; i < 8; i++) {
            fo[i] = (src[i] - mu) * rs * g1[k0 + i] + b1[k0 + i];
            v8[i] = (bf16)fo[i];
        }
        *(bf16x8*)&frag[((size_t)(rg * 16 + kc) * 64 + ln) * 8] = v8;
        if (jb == 0) {
            float4 o0 = {fo[0], fo[1], fo[2], fo[3]}, o1 = {fo[4], fo[5], fo[6], fo[7]};
            *(float4*)&h1f[(size_t)(n0 + row) * 512 + k0]     = o0;
            *(float4*)&h1f[(size_t)(n0 + row) * 512 + k0 + 4] = o1;
        }
    }
    __syncthreads();
    // GEMM: wave w -> j-groups {jb*8 + w*2, +1}, both 16-row groups
    {
        const int jgA = jb * 8 + w * 2, jgB = jgA + 1;
        const bf16* B0 = &Bp[((size_t)jgA * 16 * 64 + lane) * 8];
        const bf16* B1 = &Bp[((size_t)jgB * 16 * 64 + lane) * 8];
        f32x4 a00 = {}, a01 = {}, a10 = {}, a11 = {};
#pragma unroll
        for (int kc = 0; kc < 16; kc++) {
            bf16x8 fa0 = *(const bf16x8*)&frag[((size_t)kc * 64 + lane) * 8];
            bf16x8 fa1 = *(const bf16x8*)&frag[((size_t)(16 + kc) * 64 + lane) * 8];
            bf16x8 b0 = *(const bf16x8*)&B0[(size_t)kc * 512];
            bf16x8 b1 = *(const bf16x8*)&B1[(size_t)kc * 512];
            a00 = MF(fa0, b0, a00); a01 = MF(fa0, b1, a01);
            a10 = MF(fa1, b0, a10); a11 = MF(fa1, b1, a11);
        }
        float cb0 = bff1[jgA * 16 + m15], cb1 = bff1[jgB * 16 + m15];
#pragma unroll
        for (int r = 0; r < 4; r++) {
            int na = n0 + quad * 4 + r, nb = n0 + 16 + quad * 4 + r;
            f1b[(size_t)na * 2048 + jgA * 16 + m15] = (bf16)fmaxf(a00[r] + cb0, 0.f);
            f1b[(size_t)na * 2048 + jgB * 16 + m15] = (bf16)fmaxf(a01[r] + cb1, 0.f);
            f1b[(size_t)nb * 2048 + jgA * 16 + m15] = (bf16)fmaxf(a10[r] + cb0, 0.f);
            f1b[(size_t)nb * 2048 + jgB * 16 + m15] = (bf16)fmaxf(a11[r] + cb1, 0.f);
        }
    }
}

// ---------------------------------------------------------------------------
// FF2: ffa[n,j] = f1b@W_ff2 + bff2[j] + h1f[n,j]  (= h1 + ff, the LN2 input).
// Tile 32 x 64 (R5 fgemm layout), K=2048. grid (8, 48).
// ---------------------------------------------------------------------------
__global__ __launch_bounds__(256) void ff2_k(
    const bf16* __restrict__ A, const bf16* __restrict__ Bp,
    const float* __restrict__ bff2, const float* __restrict__ h1f,
    float* __restrict__ ffa)
{
    const int n0 = blockIdx.y * 32;
    const int j0g = blockIdx.x * 4;
    const int tid = threadIdx.x;
    const int w = tid >> 6, lane = tid & 63;
    const int quad = lane >> 4, m15 = lane & 15;
    const int r0 = (w & 1) * 16;
    const int cg = (w >> 1) * 2;
    const bf16* Arow = &A[(size_t)(n0 + r0 + m15) * 2048 + quad * 8];
    const bf16* B0 = &Bp[((size_t)(j0g + cg) * 64 * 64 + lane) * 8];
    const bf16* B1 = &Bp[((size_t)(j0g + cg + 1) * 64 * 64 + lane) * 8];
    f32x4 a0 = {}, a1 = {};
#pragma unroll 8
    for (int kc = 0; kc < 64; kc++) {
        bf16x8 af = *(const bf16x8*)&Arow[kc * 32];
        bf16x8 b0 = *(const bf16x8*)&B0[(size_t)kc * 512];
        bf16x8 b1 = *(const bf16x8*)&B1[(size_t)kc * 512];
        a0 = MF(af, b0, a0); a1 = MF(af, b1, a1);
    }
#pragma unroll
    for (int g = 0; g < 2; g++) {
        f32x4 ac = g ? a1 : a0;
        int j = (j0g + cg + g) * 16 + m15;
        float cb = bff2[j];
#pragma unroll
        for (int r = 0; r < 4; r++) {
            int n = n0 + r0 + quad * 4 + r;
            ffa[(size_t)n * 512 + j] = ac[r] + cb + h1f[(size_t)n * 512 + j];
        }
    }
}

// ---------------------------------------------------------------------------
// fus + fused LN2: reads ffa rows, LN2 in-block, K=544 frags (LN2|small5|0),
// GEMM vs BpFus slice -> fusv (+feat_fus). Block 32 rows x 64 cols; grid (7,48).
// ---------------------------------------------------------------------------
__global__ __launch_bounds__(256) void fusln_k(
    const float* __restrict__ ffa, const bf16* __restrict__ Bp,
    const float* __restrict__ g2, const float* __restrict__ b2,
    const float* __restrict__ small5, const float* __restrict__ feat_fus,
    float* __restrict__ fusv)
{
    __shared__ bf16 frag[2 * 17 * 64 * 8];    // 34 KB
    __shared__ float mu_s[32], rs_s[32];
    const int n0 = blockIdx.y * 32;
    const int jb = blockIdx.x;
    const int tid = threadIdx.x;
    const int w = tid >> 6, lane = tid & 63;
    const int quad = lane >> 4, m15 = lane & 15;

    // LN2 stats
    {
        int row = tid >> 3, part = tid & 7;
        const float* base = &ffa[(size_t)(n0 + row) * 512 + part * 64];
        float s = 0.f, sq = 0.f;
#pragma unroll
        for (int i = 0; i < 16; i++) {
            float4 v = *(const float4*)&base[i * 4];
            s += v.x + v.y + v.z + v.w;
            sq += v.x * v.x + v.y * v.y + v.z * v.z + v.w * v.w;
        }
#pragma unroll
        for (int o = 1; o < 8; o <<= 1) { s += __shfl_xor(s, o, 64); sq += __shfl_xor(sq, o, 64); }
        if (part == 0) {
            float mu = s * (1.f / 512.f);
            float var = sq * (1.f / 512.f) - mu * mu;
            mu_s[row] = mu; rs_s[row] = rsqrtf(var + 1e-5f);
        }
    }
    __syncthreads();
    // normalize -> frag LDS (K=544)
    for (int it = 0; it < 9; it++) {
        int q = tid + it * 256;
        if (q < 2176) {
            int ln = q & 63, kc = (q >> 6) % 17, rg = q / (64 * 17);
            int row = rg * 16 + (ln & 15), k0 = kc * 32 + (ln >> 4) * 8;
            int n = n0 + row;
            float mu = mu_s[row], rs = rs_s[row];
            bf16x8 v8;
#pragma unroll
            for (int i = 0; i < 8; i++) {
                int k = k0 + i;
                float val;
                if (k < 512)      val = (ffa[(size_t)n * 512 + k] - mu) * rs * g2[k] + b2[k];
                else if (k < 519) val = small5[(size_t)n * 8 + (k - 512)];
                else              val = 0.f;
                v8[i] = (bf16)val;
            }
            *(bf16x8*)&frag[((size_t)(rg * 17 + kc) * 64 + ln) * 8] = v8;
        }
    }
    __syncthreads();
    // GEMM: wave w -> j-group jb*4+w, both row groups
    {
        const int jg = jb * 4 + w;
        const bf16* B0 = &Bp[((size_t)jg * 17 * 64 + lane) * 8];
        f32x4 a0 = {}, a1 = {};
#pragma unroll
        for (int kc = 0; kc < 17; kc++) {
            bf16x8 fa0 = *(const bf16x8*)&frag[((size_t)kc * 64 + lane) * 8];
            bf16x8 fa1 = *(const bf16x8*)&frag[((size_t)(17 + kc) * 64 + lane) * 8];
            bf16x8 b0 = *(const bf16x8*)&B0[(size_t)kc * 512];
            a0 = MF(fa0, b0, a0); a1 = MF(fa1, b0, a1);
        }
        int j = jg * 16 + m15;
#pragma unroll
        for (int r = 0; r < 4; r++) {
            int na = n0 + quad * 4 + r, nb = n0 + 16 + quad * 4 + r;
            fusv[(size_t)na * 448 + j] = a0[r] + feat_fus[(size_t)(na / 6) * 448 + j];
            fusv[(size_t)nb * 448 + j] = a1[r] + feat_fus[(size_t)(nb / 6) * 448 + j];
        }
    }
}

// ---------------------------------------------------------------------------
// Next-state producer (R5 verbatim)
// ---------------------------------------------------------------------------
__device__ __forceinline__ void next_state(
    int n, int b, int t, float o0, float o1, float g0, float g1, float tc,
    const float* Wemb, const float* bemb, const float* Weff, const float* featqp,
    float* emb_dst, float* A1f, bf16* ecA1b, float* small5, float* qp, float* A1s)
{
    float d0 = g0 - o0, d1 = g1 - o1;
    if (t < 32) {
        float e = fmaxf(o0 * Wemb[t] + o1 * Wemb[32 + t] + bemb[t], 0.f);
        if (emb_dst) emb_dst[t] = e;
        A1s[t] = e;
    } else if (t < 64) {
        int c = t - 32;
        float v;
        if      (c < 8)  v = (c & 1) ? g1 : g0;
        else if (c < 16) v = (c & 1) ? o1 : o0;
        else if (c < 24) v = (c & 1) ? d1 : d0;
        else             v = tc;
        A1s[t] = v;
    }
    if (t < 7) {
        float v2 = (t==0)?o0:(t==1)?o1:(t==2)?g0:(t==3)?g1:(t==4)?d0:(t==5)?d1:tc;
        small5[n * 8 + t] = v2;
    }
    __syncthreads();
    if (t < 64) {
        A1f[(size_t)n * 64 + t] = A1s[t];
        if (t >= 32) ecA1b[(size_t)n * 288 + 256 + (t - 32)] = (bf16)A1s[t];
    }
    float acc = featqp[(size_t)b * 256 + t];
#pragma unroll 8
    for (int k = 0; k < 64; k++) acc += A1s[k] * Weff[k * 256 + t];
    qp[(size_t)n * 256 + t] = acc;
}

__global__ __launch_bounds__(256) void finish_k(
    const float* __restrict__ fusv, const float* __restrict__ Wout,
    const float* __restrict__ bout, const float* __restrict__ Wemb,
    const float* __restrict__ bemb, const float* __restrict__ loc,
    const float* __restrict__ Weff, const float* __restrict__ featqp,
    float* __restrict__ dout, float* __restrict__ emb_gen,
    float* __restrict__ A1f, bf16* __restrict__ ecA1b,
    float* __restrict__ small5, float* __restrict__ qp, int s)
{
    __shared__ float red[8];
    __shared__ float osh[2];
    __shared__ float A1s[64];
    const int n = blockIdx.x, b = n / 6, m = n % 6, t = threadIdx.x;
    float f0 = fusv[(size_t)n * 448 + t];
    float p0 = f0 * Wout[t * 2];
    float p1 = f0 * Wout[t * 2 + 1];
    if (t < 192) {
        float f1 = fusv[(size_t)n * 448 + 256 + t];
        p0 += f1 * Wout[(256 + t) * 2];
        p1 += f1 * Wout[(256 + t) * 2 + 1];
    }
#pragma unroll
    for (int o = 32; o > 0; o >>= 1) { p0 += __shfl_xor(p0, o, 64); p1 += __shfl_xor(p1, o, 64); }
    int w = t >> 6, lane = t & 63;
    if (lane == 0) { red[w] = p0; red[4 + w] = p1; }
    __syncthreads();
    if (t == 0) {
        float o0 = red[0] + red[1] + red[2] + red[3] + bout[0];
        float o1 = red[4] + red[5] + red[6] + red[7] + bout[1];
        osh[0] = o0; osh[1] = o1;
        dout[(size_t)b * 360 + m * 60 + s * 2]     = o0;
        dout[(size_t)b * 360 + m * 60 + s * 2 + 1] = o1;
    }
    __syncthreads();
    float o0 = osh[0], o1 = osh[1];
    float g0 = loc[b * 12 + m * 2], g1 = loc[b * 12 + m * 2 + 1];
    next_state(n, b, t, o0, o1, g0, g1, (float)(OBS_ + s + 1),
               Wemb, bemb, Weff, featqp,
               &emb_gen[((size_t)s * N_ + n) * 32], A1f, ecA1b, small5, qp, A1s);
}

// ---------------------------------------------------------------------------
extern "C" void kernel_launch(void* const* d_in, const int* in_sizes, int n_in,
                              void* d_out_, int out_size, void* d_ws, size_t ws_size,
                              hipStream_t stream) {
    (void)in_sizes; (void)n_in; (void)out_size; (void)ws_size;
    const float* feat  = (const float*)d_in[0];
    const float* loc   = (const float*)d_in[1];
    const float* obs   = (const float*)d_in[2];
    const float* W_emb = (const float*)d_in[3];
    const float* b_emb = (const float*)d_in[4];
    const float* W_qkv = (const float*)d_in[5];
    const float* b_qkv = (const float*)d_in[6];
    const float* W_o   = (const float*)d_in[7];
    const float* b_o   = (const float*)d_in[8];
    const float* W_ff1 = (const float*)d_in[9];
    const float* b_ff1 = (const float*)d_in[10];
    const float* W_ff2 = (const float*)d_in[11];
    const float* b_ff2 = (const float*)d_in[12];
    const float* ln1_g = (const float*)d_in[13];
    const float* ln1_b = (const float*)d_in[14];
    const float* ln2_g = (const float*)d_in[15];
    const float* ln2_b = (const float*)d_in[16];
    const float* W_fus = (const float*)d_in[17];
    const float* b_fus = (const float*)d_in[18];
    const float* W_out = (const float*)d_in[19];
    const float* b_out = (const float*)d_in[20];
    float* dout = (float*)d_out_;

    float* ws = (float*)d_ws;
    float* Weff     = ws; ws += 513 * 256;
    float* featqp   = ws; ws += 256 * 256;
    float* featv    = ws; ws += 256 * 512;
    float* featvO   = ws; ws += 256 * 512;
    float* feat_fus = ws; ws += 256 * 448;
    float* emb_obs  = ws; ws += OBS_ * B_ * 32;
    float* emb_gen  = ws; ws += HOR_ * N_ * 32;
    float* qp       = ws; ws += (size_t)N_ * 256;
    float* A1f      = ws; ws += (size_t)N_ * 64;
    float* small5   = ws; ws += (size_t)N_ * 8;
    float* h1f      = ws; ws += (size_t)N_ * 512;
    float* aF       = ws; ws += (size_t)N_ * 512;
    float* ffa      = ws; ws += (size_t)N_ * 512;
    float* fusv     = ws; ws += (size_t)N_ * 448;
    bf16* WovCat = (bf16*)ws; ws += (320 * 512) / 2;
    bf16* BpA    = (bf16*)ws; ws += (32 * 9 * 512) / 2;
    bf16* BpF1   = (bf16*)ws; ws += (128 * 16 * 512) / 2;
    bf16* BpF2   = (bf16*)ws; ws += (32 * 64 * 512) / 2;
    bf16* BpFus  = (bf16*)ws; ws += (28 * 17 * 512) / 2;
    bf16* ecA1b  = (bf16*)ws; ws += ((size_t)N_ * 288) / 2;
    bf16* f1b    = (bf16*)ws; ws += ((size_t)N_ * 2048) / 2;

    // ---- prologue ----
    emb_obs_k<<<dim3(640), dim3(256), 0, stream>>>(obs, W_emb, b_emb, emb_obs);
    weff_k<<<dim3(513), dim3(256), 0, stream>>>(W_qkv, b_qkv, Weff);
    gemm_k<<<dim3(4, 4), dim3(256), 0, stream>>>(feat, 448, Weff + 64 * 256, 256,
        featqp, nullptr, 256, 448, Weff + 512 * 256);
    wov_k<<<dim3(256), dim3(256), 0, stream>>>(W_qkv, W_o, WovCat);
    gemm_k<<<dim3(8, 4), dim3(256), 0, stream>>>(feat, 448, W_qkv + 64 * 1536 + 1024, 1536,
        featv, nullptr, 512, 448, b_qkv + 1024);
    gemm_k<<<dim3(8, 4), dim3(256), 0, stream>>>(featv, 512, W_o, 512,
        featvO, nullptr, 512, 512, b_o);
    gemm_k<<<dim3(8, 1), dim3(256), 0, stream>>>(W_qkv + 32 * 1536 + 1024, 1536, W_o, 512,
        featv, WovCat + 256 * 512, 512, 512, nullptr);
    gemm_k<<<dim3(7, 4), dim3(256), 0, stream>>>(feat, 448, W_fus + 519 * 448, 448,
        feat_fus, nullptr, 448, 448, b_fus);
    pack_k<<<dim3(72),  dim3(256), 0, stream>>>(nullptr, WovCat, 288, 9,  512,  512,  BpA);
    pack_k<<<dim3(512), dim3(256), 0, stream>>>(W_ff1, nullptr, 512, 16, 2048, 2048, BpF1);
    pack_k<<<dim3(512), dim3(256), 0, stream>>>(W_ff2, nullptr, 2048, 64, 512, 512,  BpF2);
    pack_k<<<dim3(120), dim3(256), 0, stream>>>(W_fus, nullptr, 519, 17, 448,  448,  BpFus);
    init_k<<<dim3(N_), dim3(256), 0, stream>>>(obs, emb_obs, loc, Weff, featqp,
        A1f, ecA1b, small5, qp);

    // ---- 30 sequential decode steps, 6 kernels each ----
    for (int s = 0; s < HOR_; s++) {
        attn_k<<<dim3(N_), dim3(256), 0, stream>>>(qp, emb_obs, emb_gen, ecA1b, OBS_ + s);
        agemm_k<<<dim3(8, 48), dim3(256), 0, stream>>>(ecA1b, BpA, featvO, A1f, feat, aF);
        ff1ln_k<<<dim3(16, 48), dim3(256), 0, stream>>>(aF, BpF1, ln1_g, ln1_b, b_ff1, f1b, h1f);
        ff2_k<<<dim3(8, 48), dim3(256), 0, stream>>>(f1b, BpF2, b_ff2, h1f, ffa);
        fusln_k<<<dim3(7, 48), dim3(256), 0, stream>>>(ffa, BpFus, ln2_g, ln2_b, small5, feat_fus, fusv);
        finish_k<<<dim3(N_), dim3(256), 0, stream>>>(fusv, W_out, b_out, W_emb, b_emb,
            loc, Weff, featqp, dout, emb_gen, A1f, ecA1b, small5, qp, s);
    }
}